// Round 3
// baseline (241.626 us; speedup 1.0000x reference)
//
#include <hip/hip_runtime.h>
#include <hip/hip_bf16.h>

// Problem constants
#define D       512       // embedding dim (= C)
#define K       2048      // codebook size
#define HW      1024      // 32*32
#define N_TOK   16384     // 16*HW
#define NUMEL   8388608   // 16*512*32*32

typedef __attribute__((ext_vector_type(8))) short  short8;   // 8 bf16 = 4 VGPRs
typedef __attribute__((ext_vector_type(4))) float  floatx4;

// async global->LDS DMA, 16 B per lane; LDS dest is wave-uniform base + lane*16
#define GLD_LDS16(gptr, lptr) \
    __builtin_amdgcn_global_load_lds((const __attribute__((address_space(1))) void*)(gptr), \
                                     (__attribute__((address_space(3))) void*)(lptr), 16, 0, 0)

// ---- ws layout (bytes) ----
#define WS_ZB   0           // bf16 [16384][512]
#define WS_EB   16777216    // bf16 [2048][512]
#define WS_ESQ  18874368    // f32  [2048]
#define WS_MINB 18882560    // u32  [16384]  (packed key|idx)
#define WS_LOSS 18948096    // f32  [1]
#define WS_CNT  18948100    // u32  [1]

// monotone fp32 -> sortable u32
__device__ __forceinline__ unsigned int fkey(float f) {
    unsigned int b = __float_as_uint(f);
    return b ^ ((unsigned int)((int)b >> 31) | 0x80000000u);
}

// ---------------- Kernel P: fused prep ----------------
// blocks [0,2048): z NCHW fp32 -> zb [N_TOK][D] bf16 (transpose+cast) + minb/loss/cnt init
// blocks [2048,4096): emb row (blk-2048) -> eb bf16 + e_sq
__global__ __launch_bounds__(256) void kp(const float* __restrict__ z,
                                          const float* __restrict__ emb,
                                          __hip_bfloat16* __restrict__ zb,
                                          __hip_bfloat16* __restrict__ eb,
                                          float* __restrict__ esq,
                                          unsigned int* __restrict__ minb,
                                          float* __restrict__ loss,
                                          unsigned int* __restrict__ cnt) {
    int blk = blockIdx.x;
    int tid = threadIdx.x;
    if (blk < 2048) {
        // ---- transpose+cast path ----
        if (tid < 8) minb[blk * 8 + tid] = 0xFFFFFFFFu;
        if (blk == 0) {
            if (tid == 8) *loss = 0.f;
            if (tid == 9) *cnt = 0u;
        }
        __shared__ float t[64][65];
        int b  = blk >> 7;
        int dt = (blk >> 4) & 7;
        int nt = blk & 15;
        int d0 = dt * 64, n0 = nt * 64;
        const float* zp = z + ((size_t)b * D + d0) * HW + n0;
#pragma unroll
        for (int i = 0; i < 4; ++i) {
            int e = tid + 256 * i;     // r(64) x c4(16)
            int r = e >> 4, c4 = e & 15;
            float4 v = *(const float4*)(zp + (size_t)r * HW + c4 * 4);
            t[r][c4 * 4 + 0] = v.x; t[r][c4 * 4 + 1] = v.y;
            t[r][c4 * 4 + 2] = v.z; t[r][c4 * 4 + 3] = v.w;
        }
        __syncthreads();
        __hip_bfloat16* op = zb + ((size_t)(b * HW + n0)) * D + d0;
#pragma unroll
        for (int i = 0; i < 4; ++i) {
            int e = tid + 256 * i;     // rn(64) x cd4(16)
            int rn = e >> 4, cd4 = e & 15;
            __hip_bfloat16 q0 = __float2bfloat16(t[cd4 * 4 + 0][rn]);
            __hip_bfloat16 q1 = __float2bfloat16(t[cd4 * 4 + 1][rn]);
            __hip_bfloat16 q2 = __float2bfloat16(t[cd4 * 4 + 2][rn]);
            __hip_bfloat16 q3 = __float2bfloat16(t[cd4 * 4 + 3][rn]);
            ushort4 u;
            u.x = *(unsigned short*)&q0; u.y = *(unsigned short*)&q1;
            u.z = *(unsigned short*)&q2; u.w = *(unsigned short*)&q3;
            *(ushort4*)(op + (size_t)rn * D + cd4 * 4) = u;
        }
    } else {
        // ---- codebook cast + e_sq path ----
        int k = blk - 2048;
        const float* ep = emb + (size_t)k * D;
        float s = 0.f;
        for (int d = tid; d < D; d += 256) {
            float v = ep[d];
            s += v * v;
            eb[(size_t)k * D + d] = __float2bfloat16(v);
        }
#pragma unroll
        for (int o = 32; o; o >>= 1) s += __shfl_down(s, o);
        __shared__ float ls[4];
        if ((tid & 63) == 0) ls[tid >> 6] = s;
        __syncthreads();
        if (tid == 0) esq[k] = ls[0] + ls[1] + ls[2] + ls[3];
    }
}

// ---------------- Kernel G: bf16 MFMA GEMM + fused argmin ----------------
// grid 2048 blocks, 256 threads (4 waves, 2x2 of 64x64). XCD-swizzled so the
// 16 ktile-blocks sharing an mtile (A strip) land on ONE XCD's L2.
__global__ __launch_bounds__(256) void kg(const __hip_bfloat16* __restrict__ zb,
                                          const __hip_bfloat16* __restrict__ eb,
                                          const float* __restrict__ esq,
                                          unsigned int* __restrict__ minb) {
    __shared__ __hip_bfloat16 As[128][64];   // unpadded: required by global_load_lds
    __shared__ __hip_bfloat16 Bs[128][64];

    int xcd   = blockIdx.x & 7;          // round-robin dispatch -> XCD id (heuristic)
    int li    = blockIdx.x >> 3;         // 0..255 within-XCD sequence
    int mtile = xcd * 16 + (li >> 4);    // 16 mtiles per XCD
    int ktile = li & 15;                 // 16 consecutive li share mtile

    int tid  = threadIdx.x;
    int wv   = tid >> 6;
    int lane = tid & 63;
    int wm = wv >> 1, wn = wv & 1;   // 2x2 wave grid, each wave 64x64
    int lrow  = lane & 15;
    int lquad = lane >> 4;
    int rl = lane >> 3, c8 = lane & 7;   // staging: 8 rows x 8 uint4 per wave-call

    floatx4 acc[4][4];
#pragma unroll
    for (int i = 0; i < 4; ++i)
#pragma unroll
        for (int j = 0; j < 4; ++j) acc[i][j] = (floatx4){0.f, 0.f, 0.f, 0.f};

    const uint4* Ag = (const uint4*)(zb + (size_t)mtile * 128 * D);  // [128][64] uint4
    const uint4* Bg = (const uint4*)(eb + (size_t)ktile * 128 * D);

    for (int d0 = 0; d0 < D; d0 += 64) {
        int c0 = d0 >> 3;   // uint4 col offset
#pragma unroll
        for (int ch = 0; ch < 4; ++ch) {
            int rbase = wv * 32 + ch * 8;    // wave-uniform
            GLD_LDS16(Ag + (size_t)(rbase + rl) * 64 + c0 + c8, &As[rbase][0]);
            GLD_LDS16(Bg + (size_t)(rbase + rl) * 64 + c0 + c8, &Bs[rbase][0]);
        }
        __syncthreads();
#pragma unroll
        for (int ks = 0; ks < 2; ++ks) {
            short8 af[4], bfr[4];
#pragma unroll
            for (int i = 0; i < 4; ++i) {
                af[i]  = *(const short8*)&As[wm * 64 + i * 16 + lrow][ks * 32 + lquad * 8];
                bfr[i] = *(const short8*)&Bs[wn * 64 + i * 16 + lrow][ks * 32 + lquad * 8];
            }
#pragma unroll
            for (int i = 0; i < 4; ++i)
#pragma unroll
                for (int j = 0; j < 4; ++j)
                    acc[i][j] = __builtin_amdgcn_mfma_f32_16x16x32_bf16(af[i], bfr[j], acc[i][j], 0, 0, 0);
        }
        __syncthreads();
    }

    // epilogue: dist = esq[k] - 2*dot; per-row argmin.
    // u32 key = (fkey(dist) & ~0x7FF) | idx  -> 21-bit distance key + 11-bit idx.
    // Truncation only reorders candidates within 2^-11 relative distance (<< bf16
    // noise); ties break toward smaller idx = numpy argmin semantics.
    float es[4];
#pragma unroll
    for (int j = 0; j < 4; ++j) es[j] = esq[ktile * 128 + wn * 64 + j * 16 + lrow];

#pragma unroll
    for (int i = 0; i < 4; ++i) {
#pragma unroll
        for (int r = 0; r < 4; ++r) {
            int m_g = mtile * 128 + wm * 64 + i * 16 + lquad * 4 + r;  // C/D: row=quad*4+reg
            unsigned int best = 0xFFFFFFFFu;
#pragma unroll
            for (int j = 0; j < 4; ++j) {
                float dist = es[j] - 2.0f * acc[i][j][r];
                unsigned int kidx = (unsigned int)(ktile * 128 + wn * 64 + j * 16 + lrow);
                unsigned int p = (fkey(dist) & 0xFFFFF800u) | kidx;
                best = p < best ? p : best;
            }
#pragma unroll
            for (int o = 1; o < 16; o <<= 1) {
                unsigned int other = __shfl_xor(best, o);
                best = other < best ? other : best;
            }
            if (lrow == 0) atomicMin(&minb[m_g], best);
        }
    }
}

// ---------------- Kernel O: coalesced gather + NCHW write + loss + finalize ----------------
// grid: 16 b x 8 ctile x 16 hwtile = 2048 blocks. Loss finalize fused via
// device-scope completion counter (replaces the 1-thread kf launch).
__global__ __launch_bounds__(256) void ko2(const float* __restrict__ z,
                                           const float* __restrict__ emb,
                                           const unsigned int* __restrict__ minb,
                                           float* __restrict__ out,
                                           float* __restrict__ loss,
                                           unsigned int* __restrict__ cnt) {
    __shared__ int idx[64];
    __shared__ float qt[64][65];     // [token][c], pad 65 -> conflict-free scalar access
    int blk = blockIdx.x;
    int b = blk >> 7, ct = (blk >> 4) & 7, hwt = blk & 15;
    int c0 = ct * 64, hw0 = hwt * 64;
    int tid = threadIdx.x;
    if (tid < 64) idx[tid] = (int)(minb[b * HW + hw0 + tid] & 0x7FFu);
    __syncthreads();
    // gather: 64 rows x 16 float4, coalesced 256 B per 16-lane group
#pragma unroll
    for (int i = 0; i < 4; ++i) {
        int e = tid + 256 * i;               // tr(64) x c4(16)
        int tr = e >> 4, c4 = e & 15;
        float4 v = *(const float4*)(emb + (size_t)idx[tr] * D + c0 + c4 * 4);
        qt[tr][c4 * 4 + 0] = v.x; qt[tr][c4 * 4 + 1] = v.y;
        qt[tr][c4 * 4 + 2] = v.z; qt[tr][c4 * 4 + 3] = v.w;
    }
    __syncthreads();
    float s = 0.f;
    const float* zp = z + ((size_t)b * D + c0) * HW + hw0;
    float*       op = out + ((size_t)b * D + c0) * HW + hw0;
#pragma unroll
    for (int i = 0; i < 4; ++i) {
        int e = tid + 256 * i;               // r(64 ch) x h4(16), float4 along hw
        int r = e >> 4, h4 = e & 15;
        float4 zv = *(const float4*)(zp + (size_t)r * HW + h4 * 4);
        float4 q;
        q.x = qt[h4 * 4 + 0][r]; q.y = qt[h4 * 4 + 1][r];
        q.z = qt[h4 * 4 + 2][r]; q.w = qt[h4 * 4 + 3][r];
        *(float4*)(op + (size_t)r * HW + h4 * 4) = q;
        float d0 = q.x - zv.x, d1 = q.y - zv.y, d2 = q.z - zv.z, d3 = q.w - zv.w;
        s += d0 * d0 + d1 * d1 + d2 * d2 + d3 * d3;
    }
#pragma unroll
    for (int o = 32; o; o >>= 1) s += __shfl_down(s, o);
    __shared__ float ls[4];
    if ((tid & 63) == 0) ls[tid >> 6] = s;
    __syncthreads();
    if (tid == 0) {
        atomicAdd(loss, ls[0] + ls[1] + ls[2] + ls[3]);   // device-scope
        __threadfence();
        unsigned int old = atomicAdd(cnt, 1u);
        if (old == 2047u) {                                // last block: finalize
            float tot = atomicAdd(loss, 0.0f);             // device-scope read
            out[NUMEL] = 1.25f * tot / 8388608.0f;         // q_latent + 0.25*e_latent
        }
    }
}

extern "C" void kernel_launch(void* const* d_in, const int* in_sizes, int n_in,
                              void* d_out, int out_size, void* d_ws, size_t ws_size,
                              hipStream_t stream) {
    const float* z   = (const float*)d_in[0];   // [16,512,32,32]
    const float* emb = (const float*)d_in[1];   // [2048,512]
    char* ws = (char*)d_ws;
    __hip_bfloat16* zb  = (__hip_bfloat16*)(ws + WS_ZB);
    __hip_bfloat16* eb  = (__hip_bfloat16*)(ws + WS_EB);
    float*          esq = (float*)(ws + WS_ESQ);
    unsigned int*   minb = (unsigned int*)(ws + WS_MINB);
    float*          loss = (float*)(ws + WS_LOSS);
    unsigned int*   cnt  = (unsigned int*)(ws + WS_CNT);
    float* out = (float*)d_out;

    kp <<<4096, 256, 0, stream>>>(z, emb, zb, eb, esq, minb, loss, cnt);
    kg <<<2048, 256, 0, stream>>>(zb, eb, esq, minb);
    ko2<<<2048, 256, 0, stream>>>(z, emb, minb, out, loss, cnt);
}

// Round 4
// 172.135 us; speedup vs baseline: 1.4037x; 1.4037x over previous
//
#include <hip/hip_runtime.h>
#include <hip/hip_bf16.h>

// Problem constants
#define D       512       // embedding dim (= C)
#define K       2048      // codebook size
#define HW      1024      // 32*32
#define N_TOK   16384     // 16*HW
#define NUMEL   8388608   // 16*512*32*32

typedef __attribute__((ext_vector_type(8))) short  short8;   // 8 bf16 = 4 VGPRs
typedef __attribute__((ext_vector_type(4))) float  floatx4;

// async global->LDS DMA, 16 B per lane; LDS dest is wave-uniform base + lane*16
#define GLD_LDS16(gptr, lptr) \
    __builtin_amdgcn_global_load_lds((const __attribute__((address_space(1))) void*)(gptr), \
                                     (__attribute__((address_space(3))) void*)(lptr), 16, 0, 0)

// ---- ws layout (bytes) ----
#define WS_ZB    0           // bf16 [16384][512]
#define WS_EB    16777216    // bf16 [2048][512]
#define WS_ESQ   18874368    // f32  [2048]
#define WS_MINB  18882560    // u32  [16384]  (packed 21-bit dist key | 11-bit idx)
#define WS_XSQ   18948096    // f32  [16384]  per-token sum z^2 (fp32)
#define WS_PARTS 19013632    // f32  [256]    loss partials
#define WS_CNT   19014656    // u32  [1]      completion counter
// memset0 region: WS_XSQ .. WS_CNT+4 (contiguous, 66564 B)

// monotone fp32 -> sortable u32, and its inverse
__device__ __forceinline__ unsigned int fkey(float f) {
    unsigned int b = __float_as_uint(f);
    return b ^ ((unsigned int)((int)b >> 31) | 0x80000000u);
}
__device__ __forceinline__ float unfkey(unsigned int u) {
    unsigned int b = (u & 0x80000000u) ? (u ^ 0x80000000u) : ~u;
    return __uint_as_float(b);
}

// ---------------- Kernel P: fused prep ----------------
// blocks [0,2048): z NCHW fp32 -> zb [N_TOK][D] bf16 (transpose+cast) + fp32 x_sq accumulate
// blocks [2048,4096): emb row (blk-2048) -> eb bf16 + e_sq (fp32)
__global__ __launch_bounds__(256) void kp(const float* __restrict__ z,
                                          const float* __restrict__ emb,
                                          __hip_bfloat16* __restrict__ zb,
                                          __hip_bfloat16* __restrict__ eb,
                                          float* __restrict__ esq,
                                          float* __restrict__ xsq) {
    int blk = blockIdx.x;
    int tid = threadIdx.x;
    if (blk < 2048) {
        // ---- transpose+cast path ----
        __shared__ float t[64][65];
        int b  = blk >> 7;
        int dt = (blk >> 4) & 7;
        int nt = blk & 15;
        int d0 = dt * 64, n0 = nt * 64;
        const float* zp = z + ((size_t)b * D + d0) * HW + n0;
#pragma unroll
        for (int i = 0; i < 4; ++i) {
            int e = tid + 256 * i;     // r(64 ch) x c4(16)
            int r = e >> 4, c4 = e & 15;
            float4 v = *(const float4*)(zp + (size_t)r * HW + c4 * 4);
            t[r][c4 * 4 + 0] = v.x; t[r][c4 * 4 + 1] = v.y;
            t[r][c4 * 4 + 2] = v.z; t[r][c4 * 4 + 3] = v.w;
        }
        __syncthreads();
        // x_sq partial: thread covers 16 channels of one token column
        {
            int col = tid & 63, q = tid >> 6;
            float p = 0.f;
#pragma unroll
            for (int j = 0; j < 16; ++j) {
                float v = t[q * 16 + j][col];
                p += v * v;
            }
            atomicAdd(&xsq[b * HW + n0 + col], p);   // 32 spread adds/token total
        }
        __hip_bfloat16* op = zb + ((size_t)(b * HW + n0)) * D + d0;
#pragma unroll
        for (int i = 0; i < 4; ++i) {
            int e = tid + 256 * i;     // rn(64 tok) x cd4(16)
            int rn = e >> 4, cd4 = e & 15;
            __hip_bfloat16 q0 = __float2bfloat16(t[cd4 * 4 + 0][rn]);
            __hip_bfloat16 q1 = __float2bfloat16(t[cd4 * 4 + 1][rn]);
            __hip_bfloat16 q2 = __float2bfloat16(t[cd4 * 4 + 2][rn]);
            __hip_bfloat16 q3 = __float2bfloat16(t[cd4 * 4 + 3][rn]);
            ushort4 u;
            u.x = *(unsigned short*)&q0; u.y = *(unsigned short*)&q1;
            u.z = *(unsigned short*)&q2; u.w = *(unsigned short*)&q3;
            *(ushort4*)(op + (size_t)rn * D + cd4 * 4) = u;
        }
    } else {
        // ---- codebook cast + e_sq path ----
        int k = blk - 2048;
        const float* ep = emb + (size_t)k * D;
        float s = 0.f;
        for (int d = tid; d < D; d += 256) {
            float v = ep[d];
            s += v * v;
            eb[(size_t)k * D + d] = __float2bfloat16(v);
        }
#pragma unroll
        for (int o = 32; o; o >>= 1) s += __shfl_down(s, o);
        __shared__ float ls[4];
        if ((tid & 63) == 0) ls[tid >> 6] = s;
        __syncthreads();
        if (tid == 0) esq[k] = ls[0] + ls[1] + ls[2] + ls[3];
    }
}

// ---------------- Kernel G: bf16 MFMA GEMM + fused argmin ----------------
// grid 2048 blocks (mtile = blk>>4 -> 16 consecutive blocks share the A strip,
// dispatched simultaneously across XCDs; R3's XCD swizzle regressed, reverted).
// LDS XOR swizzle: slot (r,c8) holds global col c8^(r&7) -> fragment ds_read_b128
// goes from 16-way bank conflict (rows 128 B apart) to 2-way (free).
__global__ __launch_bounds__(256) void kg(const __hip_bfloat16* __restrict__ zb,
                                          const __hip_bfloat16* __restrict__ eb,
                                          const float* __restrict__ esq,
                                          unsigned int* __restrict__ minb) {
    __shared__ __hip_bfloat16 As[128 * 64];   // flat, unpadded (global_load_lds dest)
    __shared__ __hip_bfloat16 Bs[128 * 64];

    int mtile = blockIdx.x >> 4;
    int ktile = blockIdx.x & 15;

    int tid  = threadIdx.x;
    int wv   = tid >> 6;
    int lane = tid & 63;
    int wm = wv >> 1, wn = wv & 1;   // 2x2 wave grid, each wave 64x64
    int lrow  = lane & 15;
    int lquad = lane >> 4;
    int rl = lane >> 3, c8 = lane & 7;      // staging: 8 rows x 8 uint4 per wave-call
    int csw = c8 ^ rl;                      // swizzled global col for this lane's slot
    int swz = lrow & 7;                     // read-side row swizzle

    floatx4 acc[4][4];
#pragma unroll
    for (int i = 0; i < 4; ++i)
#pragma unroll
        for (int j = 0; j < 4; ++j) acc[i][j] = (floatx4){0.f, 0.f, 0.f, 0.f};

    const uint4* Ag = (const uint4*)(zb + (size_t)mtile * 128 * D);  // [128][64] uint4
    const uint4* Bg = (const uint4*)(eb + (size_t)ktile * 128 * D);

    for (int d0 = 0; d0 < D; d0 += 64) {
        int c0 = d0 >> 3;   // uint4 col offset
#pragma unroll
        for (int ch = 0; ch < 4; ++ch) {
            int rbase = wv * 32 + ch * 8;    // wave-uniform
            GLD_LDS16(Ag + (size_t)(rbase + rl) * 64 + c0 + csw, &As[rbase * 64]);
            GLD_LDS16(Bg + (size_t)(rbase + rl) * 64 + c0 + csw, &Bs[rbase * 64]);
        }
        __syncthreads();
#pragma unroll
        for (int ks = 0; ks < 2; ++ks) {
            short8 af[4], bfr[4];
#pragma unroll
            for (int i = 0; i < 4; ++i) {
                int cL = (ks * 4 + lquad) ^ swz;          // swizzled uint4 col
                af[i]  = *(const short8*)&As[(wm * 64 + i * 16 + lrow) * 64 + (cL << 3)];
                bfr[i] = *(const short8*)&Bs[(wn * 64 + i * 16 + lrow) * 64 + (cL << 3)];
            }
#pragma unroll
            for (int i = 0; i < 4; ++i)
#pragma unroll
                for (int j = 0; j < 4; ++j)
                    acc[i][j] = __builtin_amdgcn_mfma_f32_16x16x32_bf16(af[i], bfr[j], acc[i][j], 0, 0, 0);
        }
        __syncthreads();
    }

    // epilogue: dist = esq[k] - 2*dot; argmin via u32 key = trunc-fkey | idx
    float es[4];
#pragma unroll
    for (int j = 0; j < 4; ++j) es[j] = esq[ktile * 128 + wn * 64 + j * 16 + lrow];

#pragma unroll
    for (int i = 0; i < 4; ++i) {
#pragma unroll
        for (int r = 0; r < 4; ++r) {
            int m_g = mtile * 128 + wm * 64 + i * 16 + lquad * 4 + r;  // C/D: row=quad*4+reg
            unsigned int best = 0xFFFFFFFFu;
#pragma unroll
            for (int j = 0; j < 4; ++j) {
                float dist = es[j] - 2.0f * acc[i][j][r];
                unsigned int kidx = (unsigned int)(ktile * 128 + wn * 64 + j * 16 + lrow);
                unsigned int p = (fkey(dist) & 0xFFFFF800u) | kidx;
                best = p < best ? p : best;
            }
#pragma unroll
            for (int o = 1; o < 16; o <<= 1) {
                unsigned int other = __shfl_xor(best, o);
                best = other < best ? other : best;
            }
            if (lrow == 0) atomicMin(&minb[m_g], best);
        }
    }
}

// ---------------- Kernel O: gather + NCHW write + loss from keys ----------------
// grid: 16 b x 8 ctile x 16 hwtile = 2048 blocks. z is NOT read: output = emb
// gather; loss = sum_tok(xsq + decoded min key), computed by the 256 ct==0
// blocks into partials, reduced by the last-finishing one.
__global__ __launch_bounds__(256) void ko2(const float* __restrict__ emb,
                                           const unsigned int* __restrict__ minb,
                                           const float* __restrict__ xsq,
                                           float* __restrict__ out,
                                           float* __restrict__ parts,
                                           unsigned int* __restrict__ cnt) {
    __shared__ int idx[64];
    __shared__ float qt[64][65];     // [token][c], pad 65 -> conflict-free transpose
    __shared__ float red[4];
    __shared__ int lastflag;
    int blk = blockIdx.x;
    int b = blk >> 7, ct = (blk >> 4) & 7, hwt = blk & 15;
    int c0 = ct * 64, hw0 = hwt * 64;
    int tid = threadIdx.x;
    unsigned int mykey = 0;
    if (tid < 64) {
        mykey = minb[b * HW + hw0 + tid];
        idx[tid] = (int)(mykey & 0x7FFu);
    }
    if (tid == 0) lastflag = 0;
    __syncthreads();
    // gather: 64 rows x 16 float4, 256 B coalesced per 16-lane group (L2/L3-hot codebook)
#pragma unroll
    for (int i = 0; i < 4; ++i) {
        int e = tid + 256 * i;               // tr(64) x c4(16)
        int tr = e >> 4, c4 = e & 15;
        float4 v = *(const float4*)(emb + (size_t)idx[tr] * D + c0 + c4 * 4);
        qt[tr][c4 * 4 + 0] = v.x; qt[tr][c4 * 4 + 1] = v.y;
        qt[tr][c4 * 4 + 2] = v.z; qt[tr][c4 * 4 + 3] = v.w;
    }
    __syncthreads();
    float* op = out + ((size_t)b * D + c0) * HW + hw0;
#pragma unroll
    for (int i = 0; i < 4; ++i) {
        int e = tid + 256 * i;               // r(64 ch) x h4(16), float4 along hw
        int r = e >> 4, h4 = e & 15;
        float4 q;
        q.x = qt[h4 * 4 + 0][r]; q.y = qt[h4 * 4 + 1][r];
        q.z = qt[h4 * 4 + 2][r]; q.w = qt[h4 * 4 + 3][r];
        *(float4*)(op + (size_t)r * HW + h4 * 4) = q;
    }
    // ---- loss path: only ct==0 blocks (cover all 16384 tokens exactly once) ----
    if (ct == 0) {
        if (tid < 64) {       // wave 0 only
            float v = xsq[b * HW + hw0 + tid] + unfkey(mykey & 0xFFFFF800u);
#pragma unroll
            for (int o = 32; o; o >>= 1) v += __shfl_down(v, o);
            if (tid == 0) {
                parts[b * 16 + hwt] = v;
                __threadfence();
                lastflag = (atomicAdd(cnt, 1u) == 255u);
            }
        }
        __syncthreads();
        if (lastflag) {
            __threadfence();
            float s = parts[tid];            // 256 threads, 256 partials
#pragma unroll
            for (int o = 32; o; o >>= 1) s += __shfl_down(s, o);
            if ((tid & 63) == 0) red[tid >> 6] = s;
            __syncthreads();
            if (tid == 0)
                out[NUMEL] = 1.25f * (red[0] + red[1] + red[2] + red[3]) / 8388608.0f;
        }
    }
}

extern "C" void kernel_launch(void* const* d_in, const int* in_sizes, int n_in,
                              void* d_out, int out_size, void* d_ws, size_t ws_size,
                              hipStream_t stream) {
    const float* z   = (const float*)d_in[0];   // [16,512,32,32]
    const float* emb = (const float*)d_in[1];   // [2048,512]
    char* ws = (char*)d_ws;
    __hip_bfloat16* zb   = (__hip_bfloat16*)(ws + WS_ZB);
    __hip_bfloat16* eb   = (__hip_bfloat16*)(ws + WS_EB);
    float*          esq  = (float*)(ws + WS_ESQ);
    unsigned int*   minb = (unsigned int*)(ws + WS_MINB);
    float*          xsq  = (float*)(ws + WS_XSQ);
    float*          parts= (float*)(ws + WS_PARTS);
    unsigned int*   cnt  = (unsigned int*)(ws + WS_CNT);
    float* out = (float*)d_out;

    hipMemsetAsync(minb, 0xFF, N_TOK * 4, stream);                  // u32 max
    hipMemsetAsync(xsq, 0, (WS_CNT + 4) - WS_XSQ, stream);          // xsq+parts+cnt
    kp <<<4096, 256, 0, stream>>>(z, emb, zb, eb, esq, xsq);
    kg <<<2048, 256, 0, stream>>>(zb, eb, esq, minb);
    ko2<<<2048, 256, 0, stream>>>(emb, minb, xsq, out, parts, cnt);
}

// Round 5
// 169.312 us; speedup vs baseline: 1.4271x; 1.0167x over previous
//
#include <hip/hip_runtime.h>
#include <hip/hip_bf16.h>

// Problem constants
#define D       512       // embedding dim (= C)
#define K       2048      // codebook size
#define HW      1024      // 32*32
#define N_TOK   16384     // 16*HW
#define NUMEL   8388608   // 16*512*32*32

typedef __attribute__((ext_vector_type(8))) short  short8;   // 8 bf16 = 4 VGPRs
typedef __attribute__((ext_vector_type(4))) float  floatx4;

// async global->LDS DMA, 16 B per lane; LDS dest is wave-uniform base + lane*16
#define GLD_LDS16(gptr, lptr) \
    __builtin_amdgcn_global_load_lds((const __attribute__((address_space(1))) void*)(gptr), \
                                     (__attribute__((address_space(3))) void*)(lptr), 16, 0, 0)

// ---- ws layout (bytes) ----
#define WS_ZB    0           // bf16 [16384][512]
#define WS_EB    16777216    // bf16 [2048][512]
#define WS_ESQ   18874368    // f32  [2048]
#define WS_MINB  18882560    // u32  [16384] packed (21-bit dist key | 11-bit idx); init in kp
#define WS_XSQ   18948096    // f32  [16384] per-token sum z^2        (memset 0)
#define WS_PARTS 19013632    // f32  [256]   loss partials            (memset 0)
#define WS_SCNT  19014656    // u32  [256]   per-strip completion     (memset 0)
#define WS_CNT2  19015680    // u32  [1]     global completion        (memset 0)

// monotone fp32 -> sortable u32, and its inverse
__device__ __forceinline__ unsigned int fkey(float f) {
    unsigned int b = __float_as_uint(f);
    return b ^ ((unsigned int)((int)b >> 31) | 0x80000000u);
}
__device__ __forceinline__ float unfkey(unsigned int u) {
    unsigned int b = (u & 0x80000000u) ? (u ^ 0x80000000u) : ~u;
    return __uint_as_float(b);
}
__device__ __forceinline__ unsigned int umin2(unsigned int a, unsigned int b) {
    return a < b ? a : b;
}

// ---------------- Kernel P: fused prep ----------------
// blocks [0,2048): z NCHW fp32 -> zb bf16 (transpose+cast) + xsq + minb init
// blocks [2048,4096): emb row -> eb bf16 + e_sq
__global__ __launch_bounds__(256) void kp(const float* __restrict__ z,
                                          const float* __restrict__ emb,
                                          __hip_bfloat16* __restrict__ zb,
                                          __hip_bfloat16* __restrict__ eb,
                                          float* __restrict__ esq,
                                          float* __restrict__ xsq,
                                          unsigned int* __restrict__ minb) {
    int blk = blockIdx.x;
    int tid = threadIdx.x;
    if (blk < 2048) {
        if (tid < 8) minb[blk * 8 + tid] = 0xFFFFFFFFu;
        __shared__ float t[64][65];
        __shared__ float ps[4][64];
        int b  = blk >> 7;
        int dt = (blk >> 4) & 7;
        int nt = blk & 15;
        int d0 = dt * 64, n0 = nt * 64;
        const float* zp = z + ((size_t)b * D + d0) * HW + n0;
#pragma unroll
        for (int i = 0; i < 4; ++i) {
            int e = tid + 256 * i;     // r(64 ch) x c4(16)
            int r = e >> 4, c4 = e & 15;
            float4 v = *(const float4*)(zp + (size_t)r * HW + c4 * 4);
            t[r][c4 * 4 + 0] = v.x; t[r][c4 * 4 + 1] = v.y;
            t[r][c4 * 4 + 2] = v.z; t[r][c4 * 4 + 3] = v.w;
        }
        __syncthreads();
        {   // xsq partial: quad q covers 16 channels of token col
            int col = tid & 63, q = tid >> 6;
            float p = 0.f;
#pragma unroll
            for (int j = 0; j < 16; ++j) { float v = t[q * 16 + j][col]; p += v * v; }
            ps[q][col] = p;
        }
        __syncthreads();
        if (tid < 64)
            atomicAdd(&xsq[b * HW + n0 + tid], ps[0][tid] + ps[1][tid] + ps[2][tid] + ps[3][tid]);
        __hip_bfloat16* op = zb + ((size_t)(b * HW + n0)) * D + d0;
#pragma unroll
        for (int i = 0; i < 4; ++i) {
            int e = tid + 256 * i;     // rn(64 tok) x cd4(16)
            int rn = e >> 4, cd4 = e & 15;
            __hip_bfloat16 q0 = __float2bfloat16(t[cd4 * 4 + 0][rn]);
            __hip_bfloat16 q1 = __float2bfloat16(t[cd4 * 4 + 1][rn]);
            __hip_bfloat16 q2 = __float2bfloat16(t[cd4 * 4 + 2][rn]);
            __hip_bfloat16 q3 = __float2bfloat16(t[cd4 * 4 + 3][rn]);
            ushort4 u;
            u.x = *(unsigned short*)&q0; u.y = *(unsigned short*)&q1;
            u.z = *(unsigned short*)&q2; u.w = *(unsigned short*)&q3;
            *(ushort4*)(op + (size_t)rn * D + cd4 * 4) = u;
        }
    } else {
        int k = blk - 2048;
        const float* ep = emb + (size_t)k * D;
        float s = 0.f;
        for (int d = tid; d < D; d += 256) {
            float v = ep[d];
            s += v * v;
            eb[(size_t)k * D + d] = __float2bfloat16(v);
        }
#pragma unroll
        for (int o = 32; o; o >>= 1) s += __shfl_down(s, o);
        __shared__ float ls[4];
        if ((tid & 63) == 0) ls[tid >> 6] = s;
        __syncthreads();
        if (tid == 0) esq[k] = ls[0] + ls[1] + ls[2] + ls[3];
    }
}

// ---------------- Kernel M: GEMM (A in registers) + argmin + gather + write + loss ----------------
// 512 blocks x 256 thr (2/CU). Block = 64-token strip x half the codebook (8 ktiles).
// A (64 tok x 512) lives in VGPRs: wave wt owns 32 tokens = 2 rowgroups x 16 K-frags
// (16x16x32 A layout: row=lane&15, k=(lane>>4)*8+j -> one uint4/lane/frag).
// B staged per ktile in BK=64 steps via global_load_lds (XOR col swizzle, as R4).
// Strip's 2 blocks merge via global atomicMin(minb) + scnt; last block gathers/writes.
__global__ __launch_bounds__(256, 2) void km(const __hip_bfloat16* __restrict__ zb,
                                             const __hip_bfloat16* __restrict__ eb,
                                             const float* __restrict__ esq,
                                             const float* __restrict__ emb,
                                             const float* __restrict__ xsq,
                                             unsigned int* __restrict__ minb,
                                             unsigned int* __restrict__ scnt,
                                             unsigned int* __restrict__ cnt2,
                                             float* __restrict__ parts,
                                             float* __restrict__ out) {
    __shared__ __hip_bfloat16 Bs[128 * 64];   // 16 KB, unpadded (global_load_lds dest)
    __shared__ unsigned int mint[64];
    __shared__ float qt[64][65];
    __shared__ float red[4];
    __shared__ int lastflag, finflag;

    int blk   = blockIdx.x;
    int strip = blk >> 1;          // 0..255: 64-token strip
    int kh    = blk & 1;           // codebook half
    int tid  = threadIdx.x;
    int lane = tid & 63, wv = tid >> 6;
    int wt = wv >> 1, wc = wv & 1; // wave grid: wt = token half (32), wc = code half (64)
    int lrow = lane & 15, lquad = lane >> 4;
    int rl = lane >> 3, c8 = lane & 7, csw = c8 ^ rl;   // staging swizzle

    if (tid < 64) mint[tid] = 0xFFFFFFFFu;

    // ---- A into registers: 2 rowgroups x 16 frags (K=32 each) ----
    const uint4* Ag = (const uint4*)zb + (size_t)strip * 64 * 64;  // 64 tok x 64 uint4
    short8 areg[2][16];
#pragma unroll
    for (int i = 0; i < 2; ++i)
#pragma unroll
        for (int f = 0; f < 16; ++f) {
            uint4 t4 = Ag[(size_t)(wt * 32 + i * 16 + lrow) * 64 + f * 4 + lquad];
            areg[i][f] = *(short8*)&t4;
        }

    unsigned int best[2][4];
#pragma unroll
    for (int i = 0; i < 2; ++i)
#pragma unroll
        for (int r = 0; r < 4; ++r) best[i][r] = 0xFFFFFFFFu;

    const uint4* Bg0 = (const uint4*)eb;
    int kt0 = kh * 8;
    for (int kt = kt0; kt < kt0 + 8; ++kt) {
        floatx4 acc[2][4];
#pragma unroll
        for (int i = 0; i < 2; ++i)
#pragma unroll
            for (int cf = 0; cf < 4; ++cf) acc[i][cf] = (floatx4){0.f, 0.f, 0.f, 0.f};
        const uint4* Bg = Bg0 + (size_t)kt * 128 * 64;
#pragma unroll
        for (int sd = 0; sd < 8; ++sd) {       // BK=64 steps; sd must be compile-time (areg idx)
            int c0 = sd * 8;
#pragma unroll
            for (int ch = 0; ch < 4; ++ch) {   // 16 KB: 4 waves x 4 chunks x 1 KB
                int rbase = wv * 32 + ch * 8;
                GLD_LDS16(Bg + (size_t)(rbase + rl) * 64 + c0 + csw, &Bs[rbase * 64]);
            }
            __syncthreads();
#pragma unroll
            for (int ks = 0; ks < 2; ++ks) {
                short8 bfr[4];
#pragma unroll
                for (int cf = 0; cf < 4; ++cf) {
                    int rcode = wc * 64 + cf * 16 + lrow;
                    int cc = ks * 4 + lquad;
                    bfr[cf] = *(const short8*)&Bs[rcode * 64 + ((cc ^ (rcode & 7)) << 3)];
                }
#pragma unroll
                for (int i = 0; i < 2; ++i)
#pragma unroll
                    for (int cf = 0; cf < 4; ++cf)
                        acc[i][cf] = __builtin_amdgcn_mfma_f32_16x16x32_bf16(
                            areg[i][sd * 2 + ks], bfr[cf], acc[i][cf], 0, 0, 0);
            }
            __syncthreads();
        }
        // per-ktile: fold into per-lane running best (butterfly deferred to end)
        float es[4];
#pragma unroll
        for (int cf = 0; cf < 4; ++cf) es[cf] = esq[kt * 128 + wc * 64 + cf * 16 + lrow];
#pragma unroll
        for (int i = 0; i < 2; ++i)
#pragma unroll
            for (int r = 0; r < 4; ++r) {
                unsigned int bb = best[i][r];
#pragma unroll
                for (int cf = 0; cf < 4; ++cf) {
                    float dist = es[cf] - 2.0f * acc[i][cf][r];
                    unsigned int code = (unsigned int)(kt * 128 + wc * 64 + cf * 16 + lrow);
                    bb = umin2(bb, (fkey(dist) & 0xFFFFF800u) | code);
                }
                best[i][r] = bb;
            }
    }

    // ---- merge: butterfly over 16-lane row groups, LDS atomicMin, global atomicMin ----
#pragma unroll
    for (int i = 0; i < 2; ++i)
#pragma unroll
        for (int r = 0; r < 4; ++r) {
            unsigned int bb = best[i][r];
#pragma unroll
            for (int o = 1; o < 16; o <<= 1) bb = umin2(bb, __shfl_xor(bb, o));
            if (lrow == 0) atomicMin(&mint[wt * 32 + i * 16 + lquad * 4 + r], bb);
        }
    __syncthreads();
    if (tid < 64) atomicMin(&minb[strip * 64 + tid], mint[tid]);
    if (tid == 0) {
        __threadfence();
        lastflag = (atomicAdd(&scnt[strip], 1u) == 1u);
    }
    __syncthreads();
    if (!lastflag) return;

    // ---- winner block: final keys (atomic read = device-coherent) ----
    if (tid < 64) mint[tid] = atomicMin(&minb[strip * 64 + tid], 0xFFFFFFFFu);
    __syncthreads();

    // loss partial for these 64 tokens: xsq + decoded min (esq - 2 dot)
    if (tid < 64) {
        float v = xsq[strip * 64 + tid] + unfkey(mint[tid] & 0xFFFFF800u);
#pragma unroll
        for (int o = 32; o; o >>= 1) v += __shfl_down(v, o);
        if (tid == 0) parts[strip] = v;
    }
    if (tid == 0) {
        __threadfence();
        finflag = (atomicAdd(cnt2, 1u) == 255u);
    }
    __syncthreads();
    if (finflag) {
        __threadfence();
        float s = parts[tid];              // 256 partials
#pragma unroll
        for (int o = 32; o; o >>= 1) s += __shfl_down(s, o);
        if ((tid & 63) == 0) red[tid >> 6] = s;
        __syncthreads();
        if (tid == 0)
            out[NUMEL] = 1.25f * (red[0] + red[1] + red[2] + red[3]) / 8388608.0f;
    }

    // ---- gather + NCHW write for the strip's 64 tokens ----
    int b = strip >> 4, hw0 = (strip & 15) * 64;
    for (int ct = 0; ct < 8; ++ct) {
        int c0 = ct * 64;
#pragma unroll
        for (int i = 0; i < 4; ++i) {
            int e = tid + 256 * i;           // tr(64) x c4(16)
            int tr = e >> 4, c4 = e & 15;
            float4 v = *(const float4*)(emb + (size_t)(mint[tr] & 0x7FFu) * D + c0 + c4 * 4);
            qt[tr][c4 * 4 + 0] = v.x; qt[tr][c4 * 4 + 1] = v.y;
            qt[tr][c4 * 4 + 2] = v.z; qt[tr][c4 * 4 + 3] = v.w;
        }
        __syncthreads();
        float* op = out + ((size_t)b * D + c0) * HW + hw0;
#pragma unroll
        for (int i = 0; i < 4; ++i) {
            int e = tid + 256 * i;           // r(64 ch) x h4(16)
            int r = e >> 4, h4 = e & 15;
            float4 q;
            q.x = qt[h4 * 4 + 0][r]; q.y = qt[h4 * 4 + 1][r];
            q.z = qt[h4 * 4 + 2][r]; q.w = qt[h4 * 4 + 3][r];
            *(float4*)(op + (size_t)r * HW + h4 * 4) = q;
        }
        __syncthreads();
    }
}

extern "C" void kernel_launch(void* const* d_in, const int* in_sizes, int n_in,
                              void* d_out, int out_size, void* d_ws, size_t ws_size,
                              hipStream_t stream) {
    const float* z   = (const float*)d_in[0];   // [16,512,32,32]
    const float* emb = (const float*)d_in[1];   // [2048,512]
    char* ws = (char*)d_ws;
    __hip_bfloat16* zb   = (__hip_bfloat16*)(ws + WS_ZB);
    __hip_bfloat16* eb   = (__hip_bfloat16*)(ws + WS_EB);
    float*          esq  = (float*)(ws + WS_ESQ);
    unsigned int*   minb = (unsigned int*)(ws + WS_MINB);
    float*          xsq  = (float*)(ws + WS_XSQ);
    float*          parts= (float*)(ws + WS_PARTS);
    unsigned int*   sc   = (unsigned int*)(ws + WS_SCNT);
    unsigned int*   cnt2 = (unsigned int*)(ws + WS_CNT2);
    float* out = (float*)d_out;

    hipMemsetAsync(ws + WS_XSQ, 0, (WS_CNT2 + 4) - WS_XSQ, stream);  // xsq+parts+scnt+cnt2
    kp<<<4096, 256, 0, stream>>>(z, emb, zb, eb, esq, xsq, minb);
    km<<< 512, 256, 0, stream>>>(zb, eb, esq, emb, xsq, minb, sc, cnt2, parts, out);
}